// Round 12
// baseline (476.899 us; speedup 1.0000x reference)
//
#include <hip/hip_runtime.h>

typedef unsigned short u16;
typedef short short8 __attribute__((ext_vector_type(8)));
typedef short short4v __attribute__((ext_vector_type(4)));
typedef float floatx4 __attribute__((ext_vector_type(4)));
typedef float floatx4v __attribute__((ext_vector_type(4)));

#define SQ 2048
#define NH 16
#define HD 128
#define RD 64
#define NB 2
#define LDKV 5120
#define LDQ 3072

// padded LDS strides (odd multiples of 8 u16 = 16 B)
#define LKC 136
#define LKR 72
#define LVT 72
#define LP  72

// workspace offsets (u16 units)
#define OFF_BC   ((size_t)0)
#define OFF_WT1  ((size_t)16384)
#define OFF_WT2  (OFF_WT1 + (size_t)2048 * 2048)
#define OFF_WT3  (OFF_WT2 + (size_t)5120 * 512)
#define OFF_WTO  (OFF_WT3 + (size_t)3072 * 1536)
#define OFF_KVQD (OFF_WTO + (size_t)2048 * 2048)
#define OFF_KV   (OFF_KVQD + (size_t)4096 * 2048)
#define OFF_QB   (OFF_KV + (size_t)4096 * 5120)
#define OFF_ROPE (OFF_QB + (size_t)4096 * 3072)     // 2048x32 float2 = 512 KB
#define OFF_VT   (OFF_ROPE + (size_t)262144)        // 32*128*2048 u16 = 16.8 MB
#define WS_NEED_BIG ((OFF_VT + (size_t)32 * 128 * 2048) * 2)

__device__ __forceinline__ float bf2f(u16 u) {
  union { unsigned u; float f; } v; v.u = ((unsigned)u) << 16; return v.f;
}
__device__ __forceinline__ u16 f2bf(float f) {
  union { float f; unsigned u; } v; v.f = f;
  return (u16)((v.u + 0x7FFFu + ((v.u >> 16) & 1u)) >> 16);
}
__device__ __forceinline__ void gll16(const u16* g, u16* l) {
  __builtin_amdgcn_global_load_lds((const __attribute__((address_space(1))) void*)g,
                                   (__attribute__((address_space(3))) void*)l, 16, 0, 0);
}

// ---- prep: ONE launch = convert_x + biases + 8 weight transposes + rope table.
__global__ __launch_bounds__(256) void prep(
    const float* __restrict__ x,
    const float* b0, const float* b1, const float* b2, const float* b3,
    const float* b4, const float* b5, const float* b6, const float* b7,
    const float* w0, const float* w1, const float* w2, const float* w3,
    const float* w4, const float* w5, const float* w6, const float* w7,
    u16* __restrict__ ws) {
  __shared__ u16 tile[32][33];
  const int blk = blockIdx.x, t = threadIdx.x;

  if (blk < 8192) {  // convert_x: x f32 -> bf16 at xc (= Qb overlay)
    const int i = blk * 256 + t;  // exactly 4096*2048/4 threads
    const floatx4v v = *(const floatx4v*)(x + 4 * (size_t)i);
    short4v o;
    o.x = (short)f2bf(v.x); o.y = (short)f2bf(v.y);
    o.z = (short)f2bf(v.z); o.w = (short)f2bf(v.w);
    *(short4v*)(ws + OFF_QB + 4 * (size_t)i) = o;
    return;
  }
  if (blk < 8240) {  // biases -> bc
    const int i = (blk - 8192) * 256 + t;
    if (i >= 12288) return;
    float v;
    if      (i < 512)   v = b0[i];          // kvdb
    else if (i < 2048)  v = b1[i - 512];    // qdb
    else if (i < 4096)  v = b2[i - 2048];   // kub
    else if (i < 6144)  v = b3[i - 4096];   // vub
    else if (i < 7168)  v = b4[i - 6144];   // krb
    else if (i < 9216)  v = b5[i - 7168];   // qub
    else if (i < 10240) v = b6[i - 9216];   // qrb
    else                v = b7[i - 10240];  // ob
    ws[OFF_BC + i] = f2bf(v);
    return;
  }
  if (blk >= 23600) {  // rope table: i = s*32 + j, entry = (cos, sin)
    const int i = (blk - 23600) * 256 + t;  // [0, 65536)
    const int s = i >> 5, j = i & 31;
    const float inv = exp2f(-(float)j * 0.41524101186092031f);  // 10000^(-j/32)
    float sn, cs;
    sincosf((float)s * inv, &sn, &cs);
    float* rt = (float*)(ws + OFF_ROPE);
    rt[2 * i]     = cs;
    rt[2 * i + 1] = sn;
    return;
  }
  // weight transposes: in[R][C] f32 -> out[C][R] bf16
  const int f = blk - 8240;  // [0, 15360)
  const float* in; size_t oo; int R, C, start;
  if      (f < 1024)  { in = w0; oo = OFF_WT1;                        R = 2048; C = 512;  start = 0; }
  else if (f < 4096)  { in = w1; oo = OFF_WT1 + (size_t)512 * 2048;   R = 2048; C = 1536; start = 1024; }
  else if (f < 5120)  { in = w2; oo = OFF_WT2;                        R = 512;  C = 2048; start = 4096; }
  else if (f < 6144)  { in = w3; oo = OFF_WT2 + (size_t)2048 * 512;   R = 512;  C = 2048; start = 5120; }
  else if (f < 6656)  { in = w4; oo = OFF_WT2 + (size_t)4096 * 512;   R = 512;  C = 1024; start = 6144; }
  else if (f < 9728)  { in = w5; oo = OFF_WT3;                        R = 1536; C = 2048; start = 6656; }
  else if (f < 11264) { in = w6; oo = OFF_WT3 + (size_t)2048 * 1536;  R = 1536; C = 1024; start = 9728; }
  else                { in = w7; oo = OFF_WTO;                        R = 2048; C = 2048; start = 11264; }
  u16* out = ws + oo;
  const int local = f - start, nx = C / 32;
  const int c0 = (local % nx) * 32, r0 = (local / nx) * 32;
  const int xx = t & 31, y = t >> 5;
#pragma unroll
  for (int i = 0; i < 32; i += 8)
    tile[y + i][xx] = f2bf(in[(size_t)(r0 + y + i) * C + c0 + xx]);
  __syncthreads();
#pragma unroll
  for (int i = 0; i < 32; i += 8)
    out[(size_t)(c0 + y + i) * R + r0 + xx] = tile[xx][y + i];
}

// ---- transpose_v (FALLBACK path only, when ws too small for dedicated Vt):
// V (cols 2048..4095 of KV) -> Vt overlay on KVQd. 8192 blocks.
__global__ __launch_bounds__(256) void transpose_v(u16* __restrict__ ws) {
  __shared__ u16 tile[32][33];
  const int f = blockIdx.x, t = threadIdx.x;
  const int bh = f >> 8, rem = f & 255;
  const int b = bh >> 4, hh = bh & 15;
  const int s0 = (rem & 63) * 32, d0 = (rem >> 6) * 32;
  const u16* pin = ws + OFF_KV + (size_t)b * SQ * LDKV + 2048 + (size_t)hh * HD;
  u16* pout = ws + OFF_KVQD + (size_t)bh * HD * SQ;
  const int xx = t & 31, y = t >> 5;
#pragma unroll
  for (int i = 0; i < 32; i += 8)
    tile[y + i][xx] = pin[(size_t)(s0 + y + i) * LDKV + d0 + xx];
  __syncthreads();
#pragma unroll
  for (int i = 0; i < 32; i += 8)
    pout[(size_t)(d0 + y + i) * SQ + s0 + xx] = tile[xx][y + i];
}

// ---- C[M=4096,N] = A[.,K](lda) * Bt[N,K]^T + bias; fused epilogues ----
// r7's proven body. Two param sets by block id vs `split` (r10). r12: mode 2
// (the KV GEMM) fuses the post-processing into the epilogue:
//  - cols 4096+ (Kr): RoPE applied in-register. Pair (2j,2j+1) = adjacent cols
//    = lanes l / l^1 (same quad -> same rows): one __shfl_xor + table float2.
//    Applied to UNROUNDED f32 (acc+bias) — closer to reference than the old
//    bf16 round-trip.
//  - cols 2048..4095 (V): if `vt` non-null, scatter short4 directly to
//    Vt[(b,h)][d][s] and SKIP the KV write (flash never reads KV's V cols);
//    else (fallback) plain KV write + separate transpose_v launch.
// modes: 0 = bf16 out, 1 = f32 out, 2 = KV-special.
__global__ __launch_bounds__(512, 4) void gemm_bt(
    int split, const float* __restrict__ rt, u16* __restrict__ vt,
    const u16* __restrict__ A1, int lda1, const u16* __restrict__ B1,
    const u16* __restrict__ bias1, void* __restrict__ C1, int ldc1, int m1, int N1, int K1,
    const u16* __restrict__ A2, int lda2, const u16* __restrict__ B2,
    const u16* __restrict__ bias2, void* __restrict__ C2, int ldc2, int m2, int N2, int K2) {
  __shared__ __align__(16) u16 lAk0[128 * 32];
  __shared__ __align__(16) u16 lAk1[128 * 32];
  __shared__ __align__(16) u16 lBk0[128 * 32];
  __shared__ __align__(16) u16 lBk1[128 * 32];
  int id = blockIdx.x;
  const u16 *A, *Bt, *bias; void* Cout; int lda, ldc, mode, N, K;
  if (id < split) {
    A = A1; lda = lda1; Bt = B1; bias = bias1; Cout = C1; ldc = ldc1; mode = m1; N = N1; K = K1;
  } else {
    id -= split;
    A = A2; lda = lda2; Bt = B2; bias = bias2; Cout = C2; ldc = ldc2; mode = m2; N = N2; K = K2;
  }
  const int nx = N >> 7;
  const int m0 = (id / nx) * 128, n0 = (id % nx) * 128;
  const int t = threadIdx.x;
  const int lane = t & 63, w = t >> 6;      // 8 waves
  const int wm = w & 1, wn = w >> 1;        // 2 M-halves x 4 N-quarters
  const int srow = t >> 2, scol = (t & 3) * 8;  // 512 thr cover [128][32] once
  const u16* gA = A + (size_t)(m0 + srow) * lda + scol;
  const u16* gB = Bt + (size_t)(n0 + srow) * K + scol;
  u16* const ldA0 = lAk0 + (16 * w) * 32;   // wave-uniform gll16 dests
  u16* const ldA1 = lAk1 + (16 * w) * 32;
  u16* const ldB0 = lBk0 + (16 * w) * 32;
  u16* const ldB1 = lBk1 + (16 * w) * 32;
  const int lane_m = lane & 15, lane_k = (lane >> 4) * 8;
  floatx4 acc[4][2] = {};
  for (int k0 = 0; k0 < K; k0 += 64) {
    gll16(gA + k0, ldA0);
    gll16(gA + k0 + 32, ldA1);
    gll16(gB + k0, ldB0);
    gll16(gB + k0 + 32, ldB1);
    __syncthreads();
    {
      short8 af[4], bf[2];
#pragma unroll
      for (int i = 0; i < 4; i++)
        af[i] = *(const short8*)(lAk0 + (wm * 64 + i * 16 + lane_m) * 32 + lane_k);
#pragma unroll
      for (int i = 0; i < 2; i++)
        bf[i] = *(const short8*)(lBk0 + (wn * 32 + i * 16 + lane_m) * 32 + lane_k);
#pragma unroll
      for (int mi = 0; mi < 4; mi++)
#pragma unroll
        for (int ni = 0; ni < 2; ni++)
          acc[mi][ni] = __builtin_amdgcn_mfma_f32_16x16x32_bf16(af[mi], bf[ni], acc[mi][ni], 0, 0, 0);
    }
    {
      short8 af[4], bf[2];
#pragma unroll
      for (int i = 0; i < 4; i++)
        af[i] = *(const short8*)(lAk1 + (wm * 64 + i * 16 + lane_m) * 32 + lane_k);
#pragma unroll
      for (int i = 0; i < 2; i++)
        bf[i] = *(const short8*)(lBk1 + (wn * 32 + i * 16 + lane_m) * 32 + lane_k);
#pragma unroll
      for (int mi = 0; mi < 4; mi++)
#pragma unroll
        for (int ni = 0; ni < 2; ni++)
          acc[mi][ni] = __builtin_amdgcn_mfma_f32_16x16x32_bf16(af[mi], bf[ni], acc[mi][ni], 0, 0, 0);
    }
    __syncthreads();
  }
  const int quad = lane >> 4;

  if (mode == 2 && n0 >= 2048 && n0 < 4096 && vt) {
    // V region, big-ws path: direct transposed scatter to Vt[(b,h)][d][s]
#pragma unroll
    for (int ni = 0; ni < 2; ni++) {
      const int col = n0 + wn * 32 + ni * 16 + lane_m;
      const float bv = bf2f(bias[col]);
      const int hh = (col - 2048) >> 7, d = (col - 2048) & 127;
#pragma unroll
      for (int mi = 0; mi < 4; mi++) {
        const int row = m0 + wm * 64 + mi * 16 + quad * 4;
        const int b = row >> 11, s0v = row & 2047;
        short4v o;
#pragma unroll
        for (int r = 0; r < 4; r++) o[r] = (short)f2bf(acc[mi][ni][r] + bv);
        *(short4v*)(vt + ((size_t)(b * 16 + hh) * 128 + d) * 2048 + s0v) = o;
      }
    }
    return;
  }
  if (mode == 2 && n0 >= 4096) {
    // Kr region: RoPE in epilogue (pair partner via shfl_xor lane^1)
#pragma unroll
    for (int ni = 0; ni < 2; ni++) {
      const int col = n0 + wn * 32 + ni * 16 + lane_m;
      const float bv = bf2f(bias[col]);
      const int j = ((col - 4096) & 63) >> 1;
      const bool even = !(col & 1);
      u16* pc = (u16*)Cout + (size_t)(m0 + wm * 64) * ldc + col;
#pragma unroll
      for (int mi = 0; mi < 4; mi++) {
        const int row = m0 + wm * 64 + mi * 16 + quad * 4;
#pragma unroll
        for (int r = 0; r < 4; r++) {
          const int s = (row + r) & 2047;
          const float val = acc[mi][ni][r] + bv;
          const float par = __shfl_xor(val, 1);
          const float2 t2 = *(const float2*)(rt + ((size_t)s * 32 + j) * 2);
          const float out = even ? val * t2.x - par * t2.y : val * t2.x + par * t2.y;
          pc[(size_t)(mi * 16 + quad * 4 + r) * ldc] = f2bf(out);
        }
      }
    }
    return;
  }
#pragma unroll
  for (int ni = 0; ni < 2; ni++) {
    const int col = n0 + wn * 32 + ni * 16 + lane_m;
    const float bv = bf2f(bias[col]);
#pragma unroll
    for (int mi = 0; mi < 4; mi++) {
      const int row = m0 + wm * 64 + mi * 16 + quad * 4;
      if (mode == 1) {
        float* pc = (float*)Cout + (size_t)row * ldc + col;
#pragma unroll
        for (int r = 0; r < 4; r++)
          pc[(size_t)r * ldc] = acc[mi][ni][r] + bv;
      } else {
        u16* pc = (u16*)Cout + (size_t)row * ldc + col;
#pragma unroll
        for (int r = 0; r < 4; r++)
          pc[(size_t)r * ldc] = f2bf(acc[mi][ni][r] + bv);
      }
    }
  }
}

// ---- flash attention: grid (16, 32); 8 waves, 128 q-rows/block, 64-key tiles ----
// Verified r5-r11 structure (153.7 us): reg-staged 1-deep prefetch, setprio,
// T13 defer-max, table-driven in-register rope-Q. Untouched this round.
__global__ __launch_bounds__(512, 4) void flash_attn(const u16* __restrict__ Q,
                                                     const u16* __restrict__ KV,
                                                     const u16* __restrict__ Vt,
                                                     const float* __restrict__ rt,
                                                     u16* __restrict__ Ctx) {
  __shared__ __align__(16) u16 lKc[64 * LKC];
  __shared__ __align__(16) u16 lKr[64 * LKR];
  __shared__ __align__(16) u16 lVt[128 * LVT];
  __shared__ __align__(16) u16 lP[8 * 16 * LP];
  const int t = threadIdx.x, lane = t & 63, w = t >> 6;
  const int col = blockIdx.y;
  const int qtile = (col < 16) ? (15 - (int)blockIdx.x) : (int)blockIdx.x;
  const int h = col & (NH - 1);
  const int b = col >> 4;
  const int q0 = qtile * 128;
  const int nkt = 2 * qtile + 2;
  const int lane_m = lane & 15, quad = lane >> 4, lane_k = quad * 8;

  // Q fragments (A-operand), one 16-row stripe per wave
  const int qrow = q0 + 16 * w + lane_m;
  const u16* qcp = Q + (size_t)(b * SQ + qrow) * LDQ + h * HD;
  const u16* qrp = Q + (size_t)(b * SQ + qrow) * LDQ + 2048 + h * RD;
  short8 qfc[4], qfr[2];
#pragma unroll
  for (int ks = 0; ks < 4; ks++) qfc[ks] = *(const short8*)(qcp + ks * 32 + lane_k);
  {
#pragma unroll
    for (int ks = 0; ks < 2; ks++) {
      short8 v = *(const short8*)(qrp + ks * 32 + lane_k);
#pragma unroll
      for (int p = 0; p < 4; p++) {
        const int j = ks * 16 + quad * 4 + p;  // rope pair index in [0,32)
        const float2 t2 = *(const float2*)(rt + ((size_t)qrow * 32 + j) * 2);
        const float x1 = bf2f((u16)v[2 * p]), x2 = bf2f((u16)v[2 * p + 1]);
        v[2 * p]     = (short)f2bf(x1 * t2.x - x2 * t2.y);
        v[2 * p + 1] = (short)f2bf(x1 * t2.y + x2 * t2.x);
      }
      qfr[ks] = v;
    }
  }

  floatx4 O[8] = {};
  float mrow[4], lsum[4];
#pragma unroll
  for (int r = 0; r < 4; r++) { mrow[r] = -1e30f; lsum[r] = 0.f; }

  const u16* gKc = KV + (size_t)b * SQ * LDKV + h * HD;          // + key*LDKV + d
  const u16* gKr = KV + (size_t)b * SQ * LDKV + 4096 + h * RD;   // + key*LDKV + d
  const u16* gVt = Vt + (size_t)(b * NH + h) * HD * SQ;          // + d*SQ + key
  const float C2 = 0.10412825525540364f;  // (1/sqrt(192)) * log2(e)
  const float THR = 28.8f;                // defer-max threshold: exp2(THR*C2)=8

  // register staging (global -> reg prefetch -> LDS), 512 threads
  short8 rKc[2], rKr, rVt[2];
  auto load_tile = [&](int kb) {
#pragma unroll
    for (int i = 0; i < 2; i++) {
      const int c = t + i * 512, row = c >> 4, cc = (c & 15) * 8;
      rKc[i] = *(const short8*)(gKc + (size_t)(kb + row) * LDKV + cc);
    }
    {
      const int row = t >> 3, cc = (t & 7) * 8;
      rKr = *(const short8*)(gKr + (size_t)(kb + row) * LDKV + cc);
    }
#pragma unroll
    for (int i = 0; i < 2; i++) {
      const int c = t + i * 512, row = c >> 3, cc = (c & 7) * 8;
      rVt[i] = *(const short8*)(gVt + (size_t)row * SQ + kb + cc);
    }
  };

  const int wrow_lo = q0 + 16 * w;
  const int wrow_hi = wrow_lo + 15;

  load_tile(0);
  for (int kt = 0; kt < nkt; kt++) {
    const int kb = kt * 64;
    __syncthreads();  // previous tile's LDS reads complete
#pragma unroll
    for (int i = 0; i < 2; i++) {
      const int c = t + i * 512, row = c >> 4, cc = (c & 15) * 8;
      *(short8*)(lKc + row * LKC + cc) = rKc[i];
    }
    {
      const int row = t >> 3, cc = (t & 7) * 8;
      *(short8*)(lKr + row * LKR + cc) = rKr;
    }
#pragma unroll
    for (int i = 0; i < 2; i++) {
      const int c = t + i * 512, row = c >> 3, cc = (c & 7) * 8;
      *(short8*)(lVt + row * LVT + cc) = rVt[i];
    }
    __syncthreads();
    if (kt < nkt - 1) load_tile(kb + 64);  // prefetch overlaps compute below

    if (kb <= wrow_hi) {  // wave-level skip of fully-masked tiles (barriers stay uniform)
      float ss[4][4];
      __builtin_amdgcn_s_setprio(1);
#pragma unroll
      for (int n = 0; n < 4; n++) {
        floatx4 a = {0.f, 0.f, 0.f, 0.f};
#pragma unroll
        for (int ks = 0; ks < 4; ks++) {
          const short8 kf = *(const short8*)(lKc + (n * 16 + lane_m) * LKC + ks * 32 + lane_k);
          a = __builtin_amdgcn_mfma_f32_16x16x32_bf16(qfc[ks], kf, a, 0, 0, 0);
        }
#pragma unroll
        for (int ks = 0; ks < 2; ks++) {
          const short8 kf = *(const short8*)(lKr + (n * 16 + lane_m) * LKR + ks * 32 + lane_k);
          a = __builtin_amdgcn_mfma_f32_16x16x32_bf16(qfr[ks], kf, a, 0, 0, 0);
        }
#pragma unroll
        for (int r = 0; r < 4; r++) ss[n][r] = a[r];
      }
      __builtin_amdgcn_s_setprio(0);
      if (kb + 63 > wrow_lo) {  // causal mask (partial tiles)
#pragma unroll
        for (int n = 0; n < 4; n++) {
          const int kcol = kb + n * 16 + lane_m;
#pragma unroll
          for (int r = 0; r < 4; r++) {
            const int row = wrow_lo + quad * 4 + r;
            if (kcol > row) ss[n][r] = -1e30f;
          }
        }
      }
      // per-row tile max
      float mt[4];
#pragma unroll
      for (int r = 0; r < 4; r++) {
        float m = fmaxf(fmaxf(ss[0][r], ss[1][r]), fmaxf(ss[2][r], ss[3][r]));
#pragma unroll
        for (int d = 1; d < 16; d <<= 1) m = fmaxf(m, __shfl_xor(m, d));
        mt[r] = m;
      }
      // T13 defer-max: rescale only if some row grew past THR
      const bool grow = (mt[0] > mrow[0] + THR) || (mt[1] > mrow[1] + THR) ||
                        (mt[2] > mrow[2] + THR) || (mt[3] > mrow[3] + THR);
      if (__any(grow)) {
#pragma unroll
        for (int r = 0; r < 4; r++) {
          const float mn = fmaxf(mrow[r], mt[r]);
          const float alpha = exp2f((mrow[r] - mn) * C2);
          mrow[r] = mn;
          lsum[r] *= alpha;
#pragma unroll
          for (int vb = 0; vb < 8; vb++) O[vb][r] *= alpha;
        }
      }
      float pw[4][4];
#pragma unroll
      for (int r = 0; r < 4; r++) {
        float s = 0.f;
#pragma unroll
        for (int n = 0; n < 4; n++) {
          const float p = exp2f((ss[n][r] - mrow[r]) * C2);
          pw[n][r] = p;
          s += p;
        }
#pragma unroll
        for (int d = 1; d < 16; d <<= 1) s += __shfl_xor(s, d);
        lsum[r] += s;
      }
      // P: C-layout -> LDS (per-wave region) -> A-layout
#pragma unroll
      for (int n = 0; n < 4; n++)
#pragma unroll
        for (int r = 0; r < 4; r++)
          lP[(w * 16 + quad * 4 + r) * LP + n * 16 + lane_m] = f2bf(pw[n][r]);
      asm volatile("s_waitcnt lgkmcnt(0)" ::: "memory");
      __builtin_amdgcn_s_setprio(1);
#pragma unroll
      for (int ks = 0; ks < 2; ks++) {
        const short8 pf = *(const short8*)(lP + (w * 16 + lane_m) * LP + ks * 32 + lane_k);
#pragma unroll
        for (int vb = 0; vb < 8; vb++) {
          const short8 vf = *(const short8*)(lVt + (vb * 16 + lane_m) * LVT + ks * 32 + lane_k);
          O[vb] = __builtin_amdgcn_mfma_f32_16x16x32_bf16(pf, vf, O[vb], 0, 0, 0);
        }
      }
      __builtin_amdgcn_s_setprio(0);
    }
  }
  float inv[4];
#pragma unroll
  for (int r = 0; r < 4; r++) inv[r] = 1.f / lsum[r];
#pragma unroll
  for (int vb = 0; vb < 8; vb++) {
#pragma unroll
    for (int r = 0; r < 4; r++) {
      const int row = wrow_lo + quad * 4 + r;
      Ctx[(size_t)(b * SQ + row) * 2048 + h * HD + vb * 16 + lane_m] = f2bf(O[vb][r] * inv[r]);
    }
  }
}

extern "C" void kernel_launch(void* const* d_in, const int* in_sizes, int n_in,
                              void* d_out, int out_size, void* d_ws, size_t ws_size,
                              hipStream_t stream) {
  (void)in_sizes; (void)n_in; (void)out_size;
  const float* x    = (const float*)d_in[0];
  const float* kvdw = (const float*)d_in[2];
  const float* kvdb = (const float*)d_in[3];
  const float* kuw  = (const float*)d_in[4];
  const float* kub  = (const float*)d_in[5];
  const float* vuw  = (const float*)d_in[6];
  const float* vub  = (const float*)d_in[7];
  const float* krw  = (const float*)d_in[8];
  const float* krb  = (const float*)d_in[9];
  const float* qdw  = (const float*)d_in[10];
  const float* qdb  = (const float*)d_in[11];
  const float* quw  = (const float*)d_in[12];
  const float* qub  = (const float*)d_in[13];
  const float* qrw  = (const float*)d_in[14];
  const float* qrb  = (const float*)d_in[15];
  const float* ow   = (const float*)d_in[16];
  const float* ob   = (const float*)d_in[17];

  u16* ws   = (u16*)d_ws;
  u16* bc   = ws + OFF_BC;
  u16* WT1  = ws + OFF_WT1;
  u16* WT2  = ws + OFF_WT2;
  u16* WT3  = ws + OFF_WT3;
  u16* WTo  = ws + OFF_WTO;
  u16* KVQd = ws + OFF_KVQD;
  u16* KV   = ws + OFF_KV;
  u16* Qb   = ws + OFF_QB;
  const float* rt = (const float*)(ws + OFF_ROPE);
  u16* Ctx  = WT1;    // overlays WT1..WT3 (dead by flash)
  u16* xc   = Qb;     // overlays Q (dead after G1)
  const u16* nu = (const u16*)nullptr;

  // Big-ws path: dedicated Vt buffer -> V scattered from G2 epilogue, no
  // transpose pass. Fallback (ws too small): Vt overlays KVQd, filled by a
  // separate transpose_v launch after G2+G3 (as r11).
  const bool big = ws_size >= WS_NEED_BIG;
  u16* Vt     = big ? (ws + OFF_VT) : KVQd;
  u16* vt_arg = big ? (ws + OFF_VT) : (u16*)nullptr;

  // one prep launch: convert_x + biases + 8 weight transposes + rope table
  prep<<<dim3(23856), 256, 0, stream>>>(x, kvdb, qdb, kub, vub, krb, qub, qrb, ob,
                                        kvdw, qdw, kuw, vuw, krw, quw, qrw, ow, ws);

  // G1: kv_c | q_c   (512 blocks, single param set, mode 0)
  gemm_bt<<<dim3(512), 512, 0, stream>>>(1 << 30, rt, (u16*)nullptr,
      xc, 2048, WT1, bc, KVQd, 2048, 0, 2048, 2048,
      nu, 0, nu, nu, (void*)nullptr, 0, 0, 0, 64);

  // G2+G3 fused: G2 = Kc|V|Kr (1280 blocks, mode 2: V-scatter + Kr-rope
  // fused in epilogue), G3 = Qc|Qr (768 blocks, mode 0)
  gemm_bt<<<dim3(2048), 512, 0, stream>>>(1280, rt, vt_arg,
      KVQd, 2048, WT2, bc + 2048, KV, LDKV, 2, 5120, 512,
      KVQd + 512, 2048, WT3, bc + 7168, Qb, LDQ, 0, 3072, 1536);

  if (!big)  // fallback: V was written to KV; transpose it into KVQd overlay
    transpose_v<<<dim3(8192), 256, 0, stream>>>(ws);

  flash_attn<<<dim3(16, 32), 512, 0, stream>>>(Qb, KV, Vt, rt, Ctx);

  // G4: out proj (f32 out, mode 1)
  gemm_bt<<<dim3(512), 512, 0, stream>>>(1 << 30, rt, (u16*)nullptr,
      Ctx, 2048, WTo, bc + 10240, d_out, 2048, 1, 2048, 2048,
      nu, 0, nu, nu, (void*)nullptr, 0, 0, 0, 64);
}